// Round 7
// baseline (150.000 us; speedup 1.0000x reference)
//
#include <hip/hip_runtime.h>

#define FF 20
#define NI 190         // F*(F-1)/2
#define NIP 192        // padded
#define BB 4096
#define FD 320         // F*D
#define PV 20          // padded row stride (floats) for s_v

// K1: W12p[320][192] = senet_w1[320][320] @ senet_w2[320][190], zero-padded cols
__global__ __launch_bounds__(192) void k_w12(const float* __restrict__ w1,
                                             const float* __restrict__ w2,
                                             float* __restrict__ W12p) {
    __shared__ float srow[FD];
    int r = blockIdx.x;
    for (int j = threadIdx.x; j < FD; j += 192) srow[j] = w1[r * FD + j];
    __syncthreads();
    int c = threadIdx.x;   // 0..191
    float acc = 0.f;
    if (c < NI) {
        for (int k = 0; k < FD; ++k) acc += srow[k] * w2[k * NI + c];
    }
    W12p[r * NIP + c] = acc;
}

// K2: w[4096][192] = z[4096][320] @ W12p[320][192].
// Wave layout: 64 rows x wave-uniform 8-col strip. W is read via uniform-addr
// loads (readfirstlane-forced scalar wave id -> s_load candidates, K$ path):
// zero LDS, zero per-lane VMEM for W. z staged in LDS as float4-transposed
// zb[k4][row]: reads are contiguous 1024B/instr (optimal ds_read_b128).
// LDS instrs/block-step: 40 (was 256). Grid 64x6 = 384 blocks -> all 256 CUs
// busy. FMA floor 3.2us; predicted ~5us (was ~12.8 LDS-port-bound on 192 CUs).
__global__ __launch_bounds__(256) void k_w(const float* __restrict__ z,
                                           const float* __restrict__ W12p,
                                           float* __restrict__ wout) {
    __shared__ float4 zb[2][8][64];   // [k-quad][row], double-buffered, 16 KB
    int t = threadIdx.x;
    int b0 = blockIdx.x * 64;
    int c0 = blockIdx.y * 32;
    int wv = __builtin_amdgcn_readfirstlane(t >> 6);  // wave id 0..3 (scalar)
    int lane = t & 63;                                 // row within tile
    int cw = c0 + wv * 8;                              // wave's col base (scalar)
    const float* __restrict__ Wk = W12p + cw;

    // staging task map: task = t + s*256; kq = task&7, row = task>>3
    int ka = t & 7,        ra = t >> 3;        // task0: rows 0..31
    int kb = t & 7,        rb = (t >> 3) + 32; // task1: rows 32..63

    float acc[8] = {0.f, 0.f, 0.f, 0.f, 0.f, 0.f, 0.f, 0.f};

    // prologue: stage step 0 into buf 0
    {
        float4 va = *(const float4*)&z[(size_t)(b0 + ra) * FD + ka * 4];
        float4 vb = *(const float4*)&z[(size_t)(b0 + rb) * FD + kb * 4];
        zb[0][ka][ra] = va;
        zb[0][kb][rb] = vb;
    }
    __syncthreads();

    int buf = 0;
    for (int step = 0; step < 10; ++step) {
        int k0 = step * 32;
        float4 va, vb;
        if (step < 9) {   // issue next-step global loads early (fly under compute)
            va = *(const float4*)&z[(size_t)(b0 + ra) * FD + (k0 + 32) + ka * 4];
            vb = *(const float4*)&z[(size_t)(b0 + rb) * FD + (k0 + 32) + kb * 4];
        }
        // compute on zb[buf]: per k: 8 scalar W reads + 1 VGPR z + 8 FMA
#pragma unroll
        for (int kg = 0; kg < 8; ++kg) {
            float4 zf = zb[buf][kg][lane];
            float zz[4] = {zf.x, zf.y, zf.z, zf.w};
#pragma unroll
            for (int kk = 0; kk < 4; ++kk) {
                const float* __restrict__ wr = Wk + (size_t)(k0 + kg * 4 + kk) * NIP;
                float zkv = zz[kk];
#pragma unroll
                for (int j = 0; j < 8; ++j) acc[j] = fmaf(zkv, wr[j], acc[j]);
            }
        }
        if (step < 9) {
            // buf^1 was last read in step-1 (already barrier-separated) -> safe to fill
            zb[buf ^ 1][ka][ra] = va;
            zb[buf ^ 1][kb][rb] = vb;
            __syncthreads();
            buf ^= 1;
        }
    }

    float4 o0 = make_float4(acc[0], acc[1], acc[2], acc[3]);
    float4 o1 = make_float4(acc[4], acc[5], acc[6], acc[7]);
    *(float4*)&wout[(size_t)(b0 + lane) * NIP + cw] = o0;
    *(float4*)&wout[(size_t)(b0 + lane) * NIP + cw + 4] = o1;
}

// K3: pair-major stage-once formulation — round-2 version (best measured:
// 143.3 us; the round-4 single-phase merge was +2.7 us, likely the 6->4
// blocks/CU occupancy drop).
#define SA(f, h, d) ((f) * 33 + (h) * 16 + (d))
__global__ __launch_bounds__(320) void k_main(const float* __restrict__ cb,   // [500000][16]
                                              const float* __restrict__ Wt,   // [32][16]
                                              const int* __restrict__ hidx,   // [2][B][NI]
                                              const int* __restrict__ iidx,   // [20][19]
                                              const float* __restrict__ wbuf, // [B][192]
                                              float* __restrict__ out) {      // [B][20][16]
    __shared__ int s_i0[NI], s_i1[NI];
    __shared__ float s_w[NI];
    __shared__ int s_plist[FF * 19];
    __shared__ float s_W[32 * 16];
    __shared__ __align__(16) float s_v[NI * PV];
    __shared__ float s_acc[19 * 33 + 2 * 16 + 16];

    int t = threadIdx.x;
    int b = blockIdx.x;

    if (t < NI) {
        s_i0[t] = hidx[b * NI + t];
        s_i1[t] = hidx[(BB + b) * NI + t];
        s_w[t] = wbuf[b * NIP + t];
    }
    for (int j = t; j < FF * 19; j += 320) s_plist[j] = iidx[j];
    for (int j = t; j < 512; j += 320) s_W[j] = Wt[j];
    __syncthreads();

    const float4* cb4 = (const float4*)cb;
    int q  = t & 3;    // quad within a 16-float row
    int pb = t >> 2;   // 0..79  (pair base; pairs pb, pb+80, pb+160)
    bool has3 = pb < (NI - 160);   // pb < 30

    // ---- Phase A0: gather hash0 rows (x w) ----
    float4 g0a = cb4[s_i0[pb] * 4 + q];
    float4 g0b = cb4[s_i0[pb + 80] * 4 + q];
    float4 g0c;
    if (has3) g0c = cb4[s_i0[pb + 160] * 4 + q];
    float w_a = s_w[pb], w_b = s_w[pb + 80];
    float w_c = has3 ? s_w[pb + 160] : 0.f;

    *(float4*)&s_v[pb * PV + q * 4] =
        make_float4(g0a.x * w_a, g0a.y * w_a, g0a.z * w_a, g0a.w * w_a);
    *(float4*)&s_v[(pb + 80) * PV + q * 4] =
        make_float4(g0b.x * w_b, g0b.y * w_b, g0b.z * w_b, g0b.w * w_b);
    if (has3)
        *(float4*)&s_v[(pb + 160) * PV + q * 4] =
            make_float4(g0c.x * w_c, g0c.y * w_c, g0c.z * w_c, g0c.w * w_c);
    __syncthreads();

    // ---- Issue hash1 gathers now; they fly under Phase B0's LDS work ----
    float4 g1a = cb4[s_i1[pb] * 4 + q];
    float4 g1b = cb4[s_i1[pb + 80] * 4 + q];
    float4 g1c;
    if (has3) g1c = cb4[s_i1[pb + 160] * 4 + q];

    // ---- Phase B0: per-field accumulate from LDS ----
    int f = t >> 4, d = t & 15;
    const int* pl = &s_plist[f * 19];
    float a0 = 0.f;
#pragma unroll
    for (int j = 0; j < 19; ++j) a0 += s_v[pl[j] * PV + d];
    __syncthreads();   // B0 reads done before s_v overwrite

    *(float4*)&s_v[pb * PV + q * 4] =
        make_float4(g1a.x * w_a, g1a.y * w_a, g1a.z * w_a, g1a.w * w_a);
    *(float4*)&s_v[(pb + 80) * PV + q * 4] =
        make_float4(g1b.x * w_b, g1b.y * w_b, g1b.z * w_b, g1b.w * w_b);
    if (has3)
        *(float4*)&s_v[(pb + 160) * PV + q * 4] =
            make_float4(g1c.x * w_c, g1c.y * w_c, g1c.z * w_c, g1c.w * w_c);
    __syncthreads();

    // ---- Phase B1 ----
    float a1 = 0.f;
#pragma unroll
    for (int j = 0; j < 19; ++j) a1 += s_v[pl[j] * PV + d];

    s_acc[SA(f, 0, d)] = a0;
    s_acc[SA(f, 1, d)] = a1;
    __syncthreads();

    // ---- Transform: out[b,f,d] = sum_k acc0[f][k]*W[k][d] + acc1[f][k]*W[16+k][d]
    float r = 0.f;
#pragma unroll
    for (int k = 0; k < 16; ++k) {
        r += s_acc[SA(f, 0, k)] * s_W[k * 16 + d];
        r += s_acc[SA(f, 1, k)] * s_W[(16 + k) * 16 + d];
    }
    out[b * FD + t] = r;
}

extern "C" void kernel_launch(void* const* d_in, const int* in_sizes, int n_in,
                              void* d_out, int out_size, void* d_ws, size_t ws_size,
                              hipStream_t stream) {
    const float* origin = (const float*)d_in[0];  // (B, F, D) = z
    const float* cb     = (const float*)d_in[1];  // (500000, 16)
    const float* Wt     = (const float*)d_in[2];  // (32, 16)
    const float* w1     = (const float*)d_in[3];  // (320, 320)
    const float* w2     = (const float*)d_in[4];  // (320, 190)
    const int*   hidx   = (const int*)d_in[5];    // (2, B, 190)
    const int*   iidx   = (const int*)d_in[6];    // (20, 19)
    float* out = (float*)d_out;

    float* W12p = (float*)d_ws;           // 320*192 floats
    float* wbuf = W12p + FD * NIP;        // 4096*192 floats

    k_w12<<<FD, 192, 0, stream>>>(w1, w2, W12p);
    dim3 gw(BB / 64, NIP / 32);
    k_w<<<gw, 256, 0, stream>>>(origin, W12p, wbuf);
    k_main<<<BB, 320, 0, stream>>>(cb, Wt, hidx, iidx, wbuf, out);
}

// Round 10
// 141.704 us; speedup vs baseline: 1.0585x; 1.0585x over previous
//
#include <hip/hip_runtime.h>

#define FF 20
#define NI 190         // F*(F-1)/2
#define NIP 192        // padded
#define BB 4096
#define FD 320         // F*D
#define PV 20          // padded row stride (floats) for s_v

// K1: W12p[320][192] = senet_w1[320][320] @ senet_w2[320][190], zero-padded cols
__global__ __launch_bounds__(192) void k_w12(const float* __restrict__ w1,
                                             const float* __restrict__ w2,
                                             float* __restrict__ W12p) {
    __shared__ float srow[FD];
    int r = blockIdx.x;
    for (int j = threadIdx.x; j < FD; j += 192) srow[j] = w1[r * FD + j];
    __syncthreads();
    int c = threadIdx.x;   // 0..191
    float acc = 0.f;
    if (c < NI) {
        for (int k = 0; k < FD; ++k) acc += srow[k] * w2[k * NI + c];
    }
    W12p[r * NIP + c] = acc;
}

// K2: w[4096][192] = z[4096][320] @ W12p[320][192]. 64x64 tiles, 4x4/thread.
// EXACT round-2 layout/task-maps/occupancy (measured-good, part of 143.3).
// Single change: register prefetch (T14 issue-early/write-late) — next
// k-step's 4 global float4 loads are issued BEFORE the compute phase (fly
// under the 32-k FMA loop); LDS write lands between the two existing
// barriers. Barrier count unchanged (2/step). Removes the per-step
// vmcnt(0) stall that a 4-wave 0.75-block/CU kernel cannot hide via TLP.
__global__ __launch_bounds__(256) void k_w(const float* __restrict__ z,
                                           const float* __restrict__ W12p,
                                           float* __restrict__ wout) {
    __shared__ float zT[32][68];
    __shared__ float Ws[32][64];
    int b0 = blockIdx.x * 64;
    int c0 = blockIdx.y * 64;
    int t = threadIdx.x;
    int tr = t >> 4, tc = t & 15;
    float acc[4][4];
#pragma unroll
    for (int i = 0; i < 4; ++i)
#pragma unroll
        for (int j = 0; j < 4; ++j) acc[i][j] = 0.f;

    // staging task maps (identical to round-2: task = t + s*256)
    int row0 = t >> 3,        ch0 = t & 7;   // s=0: rows 0..31
    int row1 = (t >> 3) + 32, ch1 = t & 7;   // s=1: rows 32..63
    int kr0 = t >> 4,         cq0 = t & 15;  // s=0: kr 0..15
    int kr1 = (t >> 4) + 16,  cq1 = t & 15;  // s=1: kr 16..31

    // prologue: stage step 0
    float4 vz0 = *(const float4*)&z[(b0 + row0) * FD + ch0 * 4];
    float4 vz1 = *(const float4*)&z[(b0 + row1) * FD + ch1 * 4];
    float4 vw0 = *(const float4*)&W12p[kr0 * NIP + c0 + cq0 * 4];
    float4 vw1 = *(const float4*)&W12p[kr1 * NIP + c0 + cq1 * 4];
    zT[ch0 * 4 + 0][row0] = vz0.x;
    zT[ch0 * 4 + 1][row0] = vz0.y;
    zT[ch0 * 4 + 2][row0] = vz0.z;
    zT[ch0 * 4 + 3][row0] = vz0.w;
    zT[ch1 * 4 + 0][row1] = vz1.x;
    zT[ch1 * 4 + 1][row1] = vz1.y;
    zT[ch1 * 4 + 2][row1] = vz1.z;
    zT[ch1 * 4 + 3][row1] = vz1.w;
    *(float4*)&Ws[kr0][cq0 * 4] = vw0;
    *(float4*)&Ws[kr1][cq1 * 4] = vw1;
    __syncthreads();

    for (int k0 = 0; k0 < FD; k0 += 32) {
        bool more = (k0 + 32) < FD;
        if (more) {   // issue next-step loads; they fly under the FMA loop
            vz0 = *(const float4*)&z[(b0 + row0) * FD + (k0 + 32) + ch0 * 4];
            vz1 = *(const float4*)&z[(b0 + row1) * FD + (k0 + 32) + ch1 * 4];
            vw0 = *(const float4*)&W12p[(k0 + 32 + kr0) * NIP + c0 + cq0 * 4];
            vw1 = *(const float4*)&W12p[(k0 + 32 + kr1) * NIP + c0 + cq1 * 4];
        }
#pragma unroll
        for (int k = 0; k < 32; ++k) {
            float4 zb = *(const float4*)&zT[k][tr * 4];
            float4 wv = *(const float4*)&Ws[k][tc * 4];
            float zz[4] = {zb.x, zb.y, zb.z, zb.w};
            float ww[4] = {wv.x, wv.y, wv.z, wv.w};
#pragma unroll
            for (int i = 0; i < 4; ++i)
#pragma unroll
                for (int j = 0; j < 4; ++j) acc[i][j] += zz[i] * ww[j];
        }
        if (more) {
            __syncthreads();   // all reads of current tile done
            zT[ch0 * 4 + 0][row0] = vz0.x;
            zT[ch0 * 4 + 1][row0] = vz0.y;
            zT[ch0 * 4 + 2][row0] = vz0.z;
            zT[ch0 * 4 + 3][row0] = vz0.w;
            zT[ch1 * 4 + 0][row1] = vz1.x;
            zT[ch1 * 4 + 1][row1] = vz1.y;
            zT[ch1 * 4 + 2][row1] = vz1.z;
            zT[ch1 * 4 + 3][row1] = vz1.w;
            *(float4*)&Ws[kr0][cq0 * 4] = vw0;
            *(float4*)&Ws[kr1][cq1 * 4] = vw1;
            __syncthreads();   // writes visible
        }
    }
#pragma unroll
    for (int i = 0; i < 4; ++i) {
        float4 v = make_float4(acc[i][0], acc[i][1], acc[i][2], acc[i][3]);
        *(float4*)&wout[(b0 + tr * 4 + i) * NIP + c0 + tc * 4] = v;
    }
}

// K3: pair-major stage-once formulation — byte-identical to round-2
// (best measured: 143.3 us).
#define SA(f, h, d) ((f) * 33 + (h) * 16 + (d))
__global__ __launch_bounds__(320) void k_main(const float* __restrict__ cb,   // [500000][16]
                                              const float* __restrict__ Wt,   // [32][16]
                                              const int* __restrict__ hidx,   // [2][B][NI]
                                              const int* __restrict__ iidx,   // [20][19]
                                              const float* __restrict__ wbuf, // [B][192]
                                              float* __restrict__ out) {      // [B][20][16]
    __shared__ int s_i0[NI], s_i1[NI];
    __shared__ float s_w[NI];
    __shared__ int s_plist[FF * 19];
    __shared__ float s_W[32 * 16];
    __shared__ __align__(16) float s_v[NI * PV];
    __shared__ float s_acc[19 * 33 + 2 * 16 + 16];

    int t = threadIdx.x;
    int b = blockIdx.x;

    if (t < NI) {
        s_i0[t] = hidx[b * NI + t];
        s_i1[t] = hidx[(BB + b) * NI + t];
        s_w[t] = wbuf[b * NIP + t];
    }
    for (int j = t; j < FF * 19; j += 320) s_plist[j] = iidx[j];
    for (int j = t; j < 512; j += 320) s_W[j] = Wt[j];
    __syncthreads();

    const float4* cb4 = (const float4*)cb;
    int q  = t & 3;    // quad within a 16-float row
    int pb = t >> 2;   // 0..79  (pair base; pairs pb, pb+80, pb+160)
    bool has3 = pb < (NI - 160);   // pb < 30

    // ---- Phase A0: gather hash0 rows (x w) ----
    float4 g0a = cb4[s_i0[pb] * 4 + q];
    float4 g0b = cb4[s_i0[pb + 80] * 4 + q];
    float4 g0c;
    if (has3) g0c = cb4[s_i0[pb + 160] * 4 + q];
    float w_a = s_w[pb], w_b = s_w[pb + 80];
    float w_c = has3 ? s_w[pb + 160] : 0.f;

    *(float4*)&s_v[pb * PV + q * 4] =
        make_float4(g0a.x * w_a, g0a.y * w_a, g0a.z * w_a, g0a.w * w_a);
    *(float4*)&s_v[(pb + 80) * PV + q * 4] =
        make_float4(g0b.x * w_b, g0b.y * w_b, g0b.z * w_b, g0b.w * w_b);
    if (has3)
        *(float4*)&s_v[(pb + 160) * PV + q * 4] =
            make_float4(g0c.x * w_c, g0c.y * w_c, g0c.z * w_c, g0c.w * w_c);
    __syncthreads();

    // ---- Issue hash1 gathers now; they fly under Phase B0's LDS work ----
    float4 g1a = cb4[s_i1[pb] * 4 + q];
    float4 g1b = cb4[s_i1[pb + 80] * 4 + q];
    float4 g1c;
    if (has3) g1c = cb4[s_i1[pb + 160] * 4 + q];

    // ---- Phase B0: per-field accumulate from LDS ----
    int f = t >> 4, d = t & 15;
    const int* pl = &s_plist[f * 19];
    float a0 = 0.f;
#pragma unroll
    for (int j = 0; j < 19; ++j) a0 += s_v[pl[j] * PV + d];
    __syncthreads();   // B0 reads done before s_v overwrite

    *(float4*)&s_v[pb * PV + q * 4] =
        make_float4(g1a.x * w_a, g1a.y * w_a, g1a.z * w_a, g1a.w * w_a);
    *(float4*)&s_v[(pb + 80) * PV + q * 4] =
        make_float4(g1b.x * w_b, g1b.y * w_b, g1b.z * w_b, g1b.w * w_b);
    if (has3)
        *(float4*)&s_v[(pb + 160) * PV + q * 4] =
            make_float4(g1c.x * w_c, g1c.y * w_c, g1c.z * w_c, g1c.w * w_c);
    __syncthreads();

    // ---- Phase B1 ----
    float a1 = 0.f;
#pragma unroll
    for (int j = 0; j < 19; ++j) a1 += s_v[pl[j] * PV + d];

    s_acc[SA(f, 0, d)] = a0;
    s_acc[SA(f, 1, d)] = a1;
    __syncthreads();

    // ---- Transform: out[b,f,d] = sum_k acc0[f][k]*W[k][d] + acc1[f][k]*W[16+k][d]
    float r = 0.f;
#pragma unroll
    for (int k = 0; k < 16; ++k) {
        r += s_acc[SA(f, 0, k)] * s_W[k * 16 + d];
        r += s_acc[SA(f, 1, k)] * s_W[(16 + k) * 16 + d];
    }
    out[b * FD + t] = r;
}

extern "C" void kernel_launch(void* const* d_in, const int* in_sizes, int n_in,
                              void* d_out, int out_size, void* d_ws, size_t ws_size,
                              hipStream_t stream) {
    const float* origin = (const float*)d_in[0];  // (B, F, D) = z
    const float* cb     = (const float*)d_in[1];  // (500000, 16)
    const float* Wt     = (const float*)d_in[2];  // (32, 16)
    const float* w1     = (const float*)d_in[3];  // (320, 320)
    const float* w2     = (const float*)d_in[4];  // (320, 190)
    const int*   hidx   = (const int*)d_in[5];    // (2, B, 190)
    const int*   iidx   = (const int*)d_in[6];    // (20, 19)
    float* out = (float*)d_out;

    float* W12p = (float*)d_ws;           // 320*192 floats
    float* wbuf = W12p + FD * NIP;        // 4096*192 floats

    k_w12<<<FD, 192, 0, stream>>>(w1, w2, W12p);
    dim3 gw(BB / 64, 3);
    k_w<<<gw, 256, 0, stream>>>(origin, W12p, wbuf);
    k_main<<<BB, 320, 0, stream>>>(cb, Wt, hidx, iidx, wbuf, out);
}

// Round 11
// 137.393 us; speedup vs baseline: 1.0918x; 1.0314x over previous
//
#include <hip/hip_runtime.h>

#define FF 20
#define NI 190         // F*(F-1)/2
#define NIP 192        // padded
#define BB 4096
#define FD 320         // F*D
#define PV 20          // padded row stride (floats) for s_v
#define KH 160         // K-half for split-K k_w12

// K1 (round-11: split-K x2): partial W12[h][320][192] over k in [h*160, h*160+160).
// Grid (320, 2) = 640 blocks (2.5/CU, was 1.25) and K-chain halved (160 iters,
// was 320): both the TLP and the serial-latency path improve ~2x.
// No atomics; k_w sums the two partials during staging.
__global__ __launch_bounds__(192) void k_w12(const float* __restrict__ w1,
                                             const float* __restrict__ w2,
                                             float* __restrict__ W12p) {
    __shared__ float srow[KH];
    int r = blockIdx.x;
    int h = blockIdx.y;            // K-half
    int k0 = h * KH;
    for (int j = threadIdx.x; j < KH; j += 192) srow[j] = w1[r * FD + k0 + j];
    __syncthreads();
    int c = threadIdx.x;   // 0..191
    float acc = 0.f;
    if (c < NI) {
        for (int k = 0; k < KH; ++k) acc += srow[k] * w2[(k0 + k) * NI + c];
    }
    W12p[h * (FD * NIP) + r * NIP + c] = acc;   // cols 190,191 get 0
}

// K2: w[4096][192] = z[4096][320] @ (W12a + W12b). 64x64 tiles, 4x4/thread.
// Round-7 measured-good structure (T14 register prefetch, -1.6us) with one
// addition: staging sums the two split-K partials (2 extra prefetched float4
// loads/thread/step, hidden under the 512-FMA compute phase).
__global__ __launch_bounds__(256) void k_w(const float* __restrict__ z,
                                           const float* __restrict__ W12p,
                                           float* __restrict__ wout) {
    __shared__ float zT[32][68];
    __shared__ float Ws[32][64];
    const float* __restrict__ W12b = W12p + FD * NIP;
    int b0 = blockIdx.x * 64;
    int c0 = blockIdx.y * 64;
    int t = threadIdx.x;
    int tr = t >> 4, tc = t & 15;
    float acc[4][4];
#pragma unroll
    for (int i = 0; i < 4; ++i)
#pragma unroll
        for (int j = 0; j < 4; ++j) acc[i][j] = 0.f;

    // staging task maps (identical to round-2: task = t + s*256)
    int row0 = t >> 3,        ch0 = t & 7;   // s=0: rows 0..31
    int row1 = (t >> 3) + 32, ch1 = t & 7;   // s=1: rows 32..63
    int kr0 = t >> 4,         cq0 = t & 15;  // s=0: kr 0..15
    int kr1 = (t >> 4) + 16,  cq1 = t & 15;  // s=1: kr 16..31

    // prologue: stage step 0
    float4 vz0 = *(const float4*)&z[(b0 + row0) * FD + ch0 * 4];
    float4 vz1 = *(const float4*)&z[(b0 + row1) * FD + ch1 * 4];
    float4 va0 = *(const float4*)&W12p[kr0 * NIP + c0 + cq0 * 4];
    float4 va1 = *(const float4*)&W12p[kr1 * NIP + c0 + cq1 * 4];
    float4 vb0 = *(const float4*)&W12b[kr0 * NIP + c0 + cq0 * 4];
    float4 vb1 = *(const float4*)&W12b[kr1 * NIP + c0 + cq1 * 4];
    zT[ch0 * 4 + 0][row0] = vz0.x;
    zT[ch0 * 4 + 1][row0] = vz0.y;
    zT[ch0 * 4 + 2][row0] = vz0.z;
    zT[ch0 * 4 + 3][row0] = vz0.w;
    zT[ch1 * 4 + 0][row1] = vz1.x;
    zT[ch1 * 4 + 1][row1] = vz1.y;
    zT[ch1 * 4 + 2][row1] = vz1.z;
    zT[ch1 * 4 + 3][row1] = vz1.w;
    *(float4*)&Ws[kr0][cq0 * 4] =
        make_float4(va0.x + vb0.x, va0.y + vb0.y, va0.z + vb0.z, va0.w + vb0.w);
    *(float4*)&Ws[kr1][cq1 * 4] =
        make_float4(va1.x + vb1.x, va1.y + vb1.y, va1.z + vb1.z, va1.w + vb1.w);
    __syncthreads();

    for (int k0 = 0; k0 < FD; k0 += 32) {
        bool more = (k0 + 32) < FD;
        if (more) {   // issue next-step loads; they fly under the FMA loop
            vz0 = *(const float4*)&z[(b0 + row0) * FD + (k0 + 32) + ch0 * 4];
            vz1 = *(const float4*)&z[(b0 + row1) * FD + (k0 + 32) + ch1 * 4];
            va0 = *(const float4*)&W12p[(k0 + 32 + kr0) * NIP + c0 + cq0 * 4];
            va1 = *(const float4*)&W12p[(k0 + 32 + kr1) * NIP + c0 + cq1 * 4];
            vb0 = *(const float4*)&W12b[(k0 + 32 + kr0) * NIP + c0 + cq0 * 4];
            vb1 = *(const float4*)&W12b[(k0 + 32 + kr1) * NIP + c0 + cq1 * 4];
        }
#pragma unroll
        for (int k = 0; k < 32; ++k) {
            float4 zb = *(const float4*)&zT[k][tr * 4];
            float4 wv = *(const float4*)&Ws[k][tc * 4];
            float zz[4] = {zb.x, zb.y, zb.z, zb.w};
            float ww[4] = {wv.x, wv.y, wv.z, wv.w};
#pragma unroll
            for (int i = 0; i < 4; ++i)
#pragma unroll
                for (int j = 0; j < 4; ++j) acc[i][j] += zz[i] * ww[j];
        }
        if (more) {
            __syncthreads();   // all reads of current tile done
            zT[ch0 * 4 + 0][row0] = vz0.x;
            zT[ch0 * 4 + 1][row0] = vz0.y;
            zT[ch0 * 4 + 2][row0] = vz0.z;
            zT[ch0 * 4 + 3][row0] = vz0.w;
            zT[ch1 * 4 + 0][row1] = vz1.x;
            zT[ch1 * 4 + 1][row1] = vz1.y;
            zT[ch1 * 4 + 2][row1] = vz1.z;
            zT[ch1 * 4 + 3][row1] = vz1.w;
            *(float4*)&Ws[kr0][cq0 * 4] =
                make_float4(va0.x + vb0.x, va0.y + vb0.y, va0.z + vb0.z, va0.w + vb0.w);
            *(float4*)&Ws[kr1][cq1 * 4] =
                make_float4(va1.x + vb1.x, va1.y + vb1.y, va1.z + vb1.z, va1.w + vb1.w);
            __syncthreads();   // writes visible
        }
    }
#pragma unroll
    for (int i = 0; i < 4; ++i) {
        float4 v = make_float4(acc[i][0], acc[i][1], acc[i][2], acc[i][3]);
        *(float4*)&wout[(b0 + tr * 4 + i) * NIP + c0 + tc * 4] = v;
    }
}

// K3: pair-major stage-once formulation — byte-identical to round-2
// (part of every <=143.3 configuration).
#define SA(f, h, d) ((f) * 33 + (h) * 16 + (d))
__global__ __launch_bounds__(320) void k_main(const float* __restrict__ cb,   // [500000][16]
                                              const float* __restrict__ Wt,   // [32][16]
                                              const int* __restrict__ hidx,   // [2][B][NI]
                                              const int* __restrict__ iidx,   // [20][19]
                                              const float* __restrict__ wbuf, // [B][192]
                                              float* __restrict__ out) {      // [B][20][16]
    __shared__ int s_i0[NI], s_i1[NI];
    __shared__ float s_w[NI];
    __shared__ int s_plist[FF * 19];
    __shared__ float s_W[32 * 16];
    __shared__ __align__(16) float s_v[NI * PV];
    __shared__ float s_acc[19 * 33 + 2 * 16 + 16];

    int t = threadIdx.x;
    int b = blockIdx.x;

    if (t < NI) {
        s_i0[t] = hidx[b * NI + t];
        s_i1[t] = hidx[(BB + b) * NI + t];
        s_w[t] = wbuf[b * NIP + t];
    }
    for (int j = t; j < FF * 19; j += 320) s_plist[j] = iidx[j];
    for (int j = t; j < 512; j += 320) s_W[j] = Wt[j];
    __syncthreads();

    const float4* cb4 = (const float4*)cb;
    int q  = t & 3;    // quad within a 16-float row
    int pb = t >> 2;   // 0..79  (pair base; pairs pb, pb+80, pb+160)
    bool has3 = pb < (NI - 160);   // pb < 30

    // ---- Phase A0: gather hash0 rows (x w) ----
    float4 g0a = cb4[s_i0[pb] * 4 + q];
    float4 g0b = cb4[s_i0[pb + 80] * 4 + q];
    float4 g0c;
    if (has3) g0c = cb4[s_i0[pb + 160] * 4 + q];
    float w_a = s_w[pb], w_b = s_w[pb + 80];
    float w_c = has3 ? s_w[pb + 160] : 0.f;

    *(float4*)&s_v[pb * PV + q * 4] =
        make_float4(g0a.x * w_a, g0a.y * w_a, g0a.z * w_a, g0a.w * w_a);
    *(float4*)&s_v[(pb + 80) * PV + q * 4] =
        make_float4(g0b.x * w_b, g0b.y * w_b, g0b.z * w_b, g0b.w * w_b);
    if (has3)
        *(float4*)&s_v[(pb + 160) * PV + q * 4] =
            make_float4(g0c.x * w_c, g0c.y * w_c, g0c.z * w_c, g0c.w * w_c);
    __syncthreads();

    // ---- Issue hash1 gathers now; they fly under Phase B0's LDS work ----
    float4 g1a = cb4[s_i1[pb] * 4 + q];
    float4 g1b = cb4[s_i1[pb + 80] * 4 + q];
    float4 g1c;
    if (has3) g1c = cb4[s_i1[pb + 160] * 4 + q];

    // ---- Phase B0: per-field accumulate from LDS ----
    int f = t >> 4, d = t & 15;
    const int* pl = &s_plist[f * 19];
    float a0 = 0.f;
#pragma unroll
    for (int j = 0; j < 19; ++j) a0 += s_v[pl[j] * PV + d];
    __syncthreads();   // B0 reads done before s_v overwrite

    *(float4*)&s_v[pb * PV + q * 4] =
        make_float4(g1a.x * w_a, g1a.y * w_a, g1a.z * w_a, g1a.w * w_a);
    *(float4*)&s_v[(pb + 80) * PV + q * 4] =
        make_float4(g1b.x * w_b, g1b.y * w_b, g1b.z * w_b, g1b.w * w_b);
    if (has3)
        *(float4*)&s_v[(pb + 160) * PV + q * 4] =
            make_float4(g1c.x * w_c, g1c.y * w_c, g1c.z * w_c, g1c.w * w_c);
    __syncthreads();

    // ---- Phase B1 ----
    float a1 = 0.f;
#pragma unroll
    for (int j = 0; j < 19; ++j) a1 += s_v[pl[j] * PV + d];

    s_acc[SA(f, 0, d)] = a0;
    s_acc[SA(f, 1, d)] = a1;
    __syncthreads();

    // ---- Transform: out[b,f,d] = sum_k acc0[f][k]*W[k][d] + acc1[f][k]*W[16+k][d]
    float r = 0.f;
#pragma unroll
    for (int k = 0; k < 16; ++k) {
        r += s_acc[SA(f, 0, k)] * s_W[k * 16 + d];
        r += s_acc[SA(f, 1, k)] * s_W[(16 + k) * 16 + d];
    }
    out[b * FD + t] = r;
}

extern "C" void kernel_launch(void* const* d_in, const int* in_sizes, int n_in,
                              void* d_out, int out_size, void* d_ws, size_t ws_size,
                              hipStream_t stream) {
    const float* origin = (const float*)d_in[0];  // (B, F, D) = z
    const float* cb     = (const float*)d_in[1];  // (500000, 16)
    const float* Wt     = (const float*)d_in[2];  // (32, 16)
    const float* w1     = (const float*)d_in[3];  // (320, 320)
    const float* w2     = (const float*)d_in[4];  // (320, 190)
    const int*   hidx   = (const int*)d_in[5];    // (2, B, 190)
    const int*   iidx   = (const int*)d_in[6];    // (20, 19)
    float* out = (float*)d_out;

    float* W12p = (float*)d_ws;               // 2 x 320*192 floats (split-K partials)
    float* wbuf = W12p + 2 * FD * NIP;        // 4096*192 floats

    k_w12<<<dim3(FD, 2), 192, 0, stream>>>(w1, w2, W12p);
    dim3 gw(BB / 64, 3);
    k_w<<<gw, 256, 0, stream>>>(origin, W12p, wbuf);
    k_main<<<BB, 320, 0, stream>>>(cb, Wt, hidx, iidx, wbuf, out);
}

// Round 12
// 135.666 us; speedup vs baseline: 1.1057x; 1.0127x over previous
//
#include <hip/hip_runtime.h>

#define FF 20
#define NI 190         // F*(F-1)/2
#define NIP 192        // padded
#define BB 4096
#define FD 320         // F*D
#define PV 20          // padded row stride (floats) for s_v
#define KH 160         // K-half (both split-K levels)

// K1 (split-K x2, measured -4.3us in r11 combo): partial W12[h][320][192]
// over k in [h*160, h*160+160). Grid (320,2): 2.5 blocks/CU, K-chain 160.
__global__ __launch_bounds__(192) void k_w12(const float* __restrict__ w1,
                                             const float* __restrict__ w2,
                                             float* __restrict__ W12p) {
    __shared__ float srow[KH];
    int r = blockIdx.x;
    int h = blockIdx.y;            // K-half
    int k0 = h * KH;
    for (int j = threadIdx.x; j < KH; j += 192) srow[j] = w1[r * FD + k0 + j];
    __syncthreads();
    int c = threadIdx.x;   // 0..191
    float acc = 0.f;
    if (c < NI) {
        for (int k = 0; k < KH; ++k) acc += srow[k] * w2[(k0 + k) * NI + c];
    }
    W12p[h * (FD * NIP) + r * NIP + c] = acc;   // cols 190,191 get 0
}

// K2 (round-12: split-K x2 over FD): partial w[h][4096][192] over W12-rows
// [h*160, h*160+160). Grid (64,3,2) = 384 blocks (1.5/CU, was 0.75 with 64
// CUs idle); serial step count halves (5, was 10). The 4x4/thread tile,
// T14 register prefetch, and FMA:LDS ratio are UNCHANGED (shrinking the
// tile instead would halve FMA per ds_read — rejected). k_main sums the
// two partials during its staging read.
__global__ __launch_bounds__(256) void k_w(const float* __restrict__ z,
                                           const float* __restrict__ W12p,
                                           float* __restrict__ wout) {
    __shared__ float zT[32][68];
    __shared__ float Ws[32][64];
    const float* __restrict__ W12b = W12p + FD * NIP;
    int b0 = blockIdx.x * 64;
    int c0 = blockIdx.y * 64;
    int kbase = blockIdx.z * KH;   // K-half base
    int t = threadIdx.x;
    int tr = t >> 4, tc = t & 15;
    float acc[4][4];
#pragma unroll
    for (int i = 0; i < 4; ++i)
#pragma unroll
        for (int j = 0; j < 4; ++j) acc[i][j] = 0.f;

    // staging task maps (identical to round-2: task = t + s*256)
    int row0 = t >> 3,        ch0 = t & 7;   // s=0: rows 0..31
    int row1 = (t >> 3) + 32, ch1 = t & 7;   // s=1: rows 32..63
    int kr0 = t >> 4,         cq0 = t & 15;  // s=0: kr 0..15
    int kr1 = (t >> 4) + 16,  cq1 = t & 15;  // s=1: kr 16..31

    // prologue: stage step 0 of this K-half
    float4 vz0 = *(const float4*)&z[(b0 + row0) * FD + kbase + ch0 * 4];
    float4 vz1 = *(const float4*)&z[(b0 + row1) * FD + kbase + ch1 * 4];
    float4 va0 = *(const float4*)&W12p[(kbase + kr0) * NIP + c0 + cq0 * 4];
    float4 va1 = *(const float4*)&W12p[(kbase + kr1) * NIP + c0 + cq1 * 4];
    float4 vb0 = *(const float4*)&W12b[(kbase + kr0) * NIP + c0 + cq0 * 4];
    float4 vb1 = *(const float4*)&W12b[(kbase + kr1) * NIP + c0 + cq1 * 4];
    zT[ch0 * 4 + 0][row0] = vz0.x;
    zT[ch0 * 4 + 1][row0] = vz0.y;
    zT[ch0 * 4 + 2][row0] = vz0.z;
    zT[ch0 * 4 + 3][row0] = vz0.w;
    zT[ch1 * 4 + 0][row1] = vz1.x;
    zT[ch1 * 4 + 1][row1] = vz1.y;
    zT[ch1 * 4 + 2][row1] = vz1.z;
    zT[ch1 * 4 + 3][row1] = vz1.w;
    *(float4*)&Ws[kr0][cq0 * 4] =
        make_float4(va0.x + vb0.x, va0.y + vb0.y, va0.z + vb0.z, va0.w + vb0.w);
    *(float4*)&Ws[kr1][cq1 * 4] =
        make_float4(va1.x + vb1.x, va1.y + vb1.y, va1.z + vb1.z, va1.w + vb1.w);
    __syncthreads();

    for (int k0 = 0; k0 < KH; k0 += 32) {
        bool more = (k0 + 32) < KH;
        if (more) {   // issue next-step loads; they fly under the FMA loop
            vz0 = *(const float4*)&z[(b0 + row0) * FD + kbase + (k0 + 32) + ch0 * 4];
            vz1 = *(const float4*)&z[(b0 + row1) * FD + kbase + (k0 + 32) + ch1 * 4];
            va0 = *(const float4*)&W12p[(kbase + k0 + 32 + kr0) * NIP + c0 + cq0 * 4];
            va1 = *(const float4*)&W12p[(kbase + k0 + 32 + kr1) * NIP + c0 + cq1 * 4];
            vb0 = *(const float4*)&W12b[(kbase + k0 + 32 + kr0) * NIP + c0 + cq0 * 4];
            vb1 = *(const float4*)&W12b[(kbase + k0 + 32 + kr1) * NIP + c0 + cq1 * 4];
        }
#pragma unroll
        for (int k = 0; k < 32; ++k) {
            float4 zb = *(const float4*)&zT[k][tr * 4];
            float4 wv = *(const float4*)&Ws[k][tc * 4];
            float zz[4] = {zb.x, zb.y, zb.z, zb.w};
            float ww[4] = {wv.x, wv.y, wv.z, wv.w};
#pragma unroll
            for (int i = 0; i < 4; ++i)
#pragma unroll
                for (int j = 0; j < 4; ++j) acc[i][j] += zz[i] * ww[j];
        }
        if (more) {
            __syncthreads();   // all reads of current tile done
            zT[ch0 * 4 + 0][row0] = vz0.x;
            zT[ch0 * 4 + 1][row0] = vz0.y;
            zT[ch0 * 4 + 2][row0] = vz0.z;
            zT[ch0 * 4 + 3][row0] = vz0.w;
            zT[ch1 * 4 + 0][row1] = vz1.x;
            zT[ch1 * 4 + 1][row1] = vz1.y;
            zT[ch1 * 4 + 2][row1] = vz1.z;
            zT[ch1 * 4 + 3][row1] = vz1.w;
            *(float4*)&Ws[kr0][cq0 * 4] =
                make_float4(va0.x + vb0.x, va0.y + vb0.y, va0.z + vb0.z, va0.w + vb0.w);
            *(float4*)&Ws[kr1][cq1 * 4] =
                make_float4(va1.x + vb1.x, va1.y + vb1.y, va1.z + vb1.z, va1.w + vb1.w);
            __syncthreads();   // writes visible
        }
    }
#pragma unroll
    for (int i = 0; i < 4; ++i) {
        float4 v = make_float4(acc[i][0], acc[i][1], acc[i][2], acc[i][3]);
        *(float4*)&wout[(size_t)blockIdx.z * (BB * NIP) +
                        (b0 + tr * 4 + i) * NIP + c0 + tc * 4] = v;
    }
}

// K3: pair-major stage-once (round-2 core, in every best config).
// One change vs r11: s_w sums the two k_w split-K partials.
#define SA(f, h, d) ((f) * 33 + (h) * 16 + (d))
__global__ __launch_bounds__(320) void k_main(const float* __restrict__ cb,   // [500000][16]
                                              const float* __restrict__ Wt,   // [32][16]
                                              const int* __restrict__ hidx,   // [2][B][NI]
                                              const int* __restrict__ iidx,   // [20][19]
                                              const float* __restrict__ wbuf, // [2][B][192]
                                              float* __restrict__ out) {      // [B][20][16]
    __shared__ int s_i0[NI], s_i1[NI];
    __shared__ float s_w[NI];
    __shared__ int s_plist[FF * 19];
    __shared__ float s_W[32 * 16];
    __shared__ __align__(16) float s_v[NI * PV];
    __shared__ float s_acc[19 * 33 + 2 * 16 + 16];

    int t = threadIdx.x;
    int b = blockIdx.x;

    if (t < NI) {
        s_i0[t] = hidx[b * NI + t];
        s_i1[t] = hidx[(BB + b) * NI + t];
        s_w[t] = wbuf[b * NIP + t] + wbuf[BB * NIP + b * NIP + t];
    }
    for (int j = t; j < FF * 19; j += 320) s_plist[j] = iidx[j];
    for (int j = t; j < 512; j += 320) s_W[j] = Wt[j];
    __syncthreads();

    const float4* cb4 = (const float4*)cb;
    int q  = t & 3;    // quad within a 16-float row
    int pb = t >> 2;   // 0..79  (pair base; pairs pb, pb+80, pb+160)
    bool has3 = pb < (NI - 160);   // pb < 30

    // ---- Phase A0: gather hash0 rows (x w) ----
    float4 g0a = cb4[s_i0[pb] * 4 + q];
    float4 g0b = cb4[s_i0[pb + 80] * 4 + q];
    float4 g0c;
    if (has3) g0c = cb4[s_i0[pb + 160] * 4 + q];
    float w_a = s_w[pb], w_b = s_w[pb + 80];
    float w_c = has3 ? s_w[pb + 160] : 0.f;

    *(float4*)&s_v[pb * PV + q * 4] =
        make_float4(g0a.x * w_a, g0a.y * w_a, g0a.z * w_a, g0a.w * w_a);
    *(float4*)&s_v[(pb + 80) * PV + q * 4] =
        make_float4(g0b.x * w_b, g0b.y * w_b, g0b.z * w_b, g0b.w * w_b);
    if (has3)
        *(float4*)&s_v[(pb + 160) * PV + q * 4] =
            make_float4(g0c.x * w_c, g0c.y * w_c, g0c.z * w_c, g0c.w * w_c);
    __syncthreads();

    // ---- Issue hash1 gathers now; they fly under Phase B0's LDS work ----
    float4 g1a = cb4[s_i1[pb] * 4 + q];
    float4 g1b = cb4[s_i1[pb + 80] * 4 + q];
    float4 g1c;
    if (has3) g1c = cb4[s_i1[pb + 160] * 4 + q];

    // ---- Phase B0: per-field accumulate from LDS ----
    int f = t >> 4, d = t & 15;
    const int* pl = &s_plist[f * 19];
    float a0 = 0.f;
#pragma unroll
    for (int j = 0; j < 19; ++j) a0 += s_v[pl[j] * PV + d];
    __syncthreads();   // B0 reads done before s_v overwrite

    *(float4*)&s_v[pb * PV + q * 4] =
        make_float4(g1a.x * w_a, g1a.y * w_a, g1a.z * w_a, g1a.w * w_a);
    *(float4*)&s_v[(pb + 80) * PV + q * 4] =
        make_float4(g1b.x * w_b, g1b.y * w_b, g1b.z * w_b, g1b.w * w_b);
    if (has3)
        *(float4*)&s_v[(pb + 160) * PV + q * 4] =
            make_float4(g1c.x * w_c, g1c.y * w_c, g1c.z * w_c, g1c.w * w_c);
    __syncthreads();

    // ---- Phase B1 ----
    float a1 = 0.f;
#pragma unroll
    for (int j = 0; j < 19; ++j) a1 += s_v[pl[j] * PV + d];

    s_acc[SA(f, 0, d)] = a0;
    s_acc[SA(f, 1, d)] = a1;
    __syncthreads();

    // ---- Transform: out[b,f,d] = sum_k acc0[f][k]*W[k][d] + acc1[f][k]*W[16+k][d]
    float r = 0.f;
#pragma unroll
    for (int k = 0; k < 16; ++k) {
        r += s_acc[SA(f, 0, k)] * s_W[k * 16 + d];
        r += s_acc[SA(f, 1, k)] * s_W[(16 + k) * 16 + d];
    }
    out[b * FD + t] = r;
}

extern "C" void kernel_launch(void* const* d_in, const int* in_sizes, int n_in,
                              void* d_out, int out_size, void* d_ws, size_t ws_size,
                              hipStream_t stream) {
    const float* origin = (const float*)d_in[0];  // (B, F, D) = z
    const float* cb     = (const float*)d_in[1];  // (500000, 16)
    const float* Wt     = (const float*)d_in[2];  // (32, 16)
    const float* w1     = (const float*)d_in[3];  // (320, 320)
    const float* w2     = (const float*)d_in[4];  // (320, 190)
    const int*   hidx   = (const int*)d_in[5];    // (2, B, 190)
    const int*   iidx   = (const int*)d_in[6];    // (20, 19)
    float* out = (float*)d_out;

    float* W12p = (float*)d_ws;               // 2 x 320*192 floats (split-K partials)
    float* wbuf = W12p + 2 * FD * NIP;        // 2 x 4096*192 floats (split-K partials)

    k_w12<<<dim3(FD, 2), 192, 0, stream>>>(w1, w2, W12p);
    dim3 gw(BB / 64, 3, 2);
    k_w<<<gw, 256, 0, stream>>>(origin, W12p, wbuf);
    k_main<<<BB, 320, 0, stream>>>(cb, Wt, hidx, iidx, wbuf, out);
}

// Round 13
// 134.715 us; speedup vs baseline: 1.1135x; 1.0071x over previous
//
#include <hip/hip_runtime.h>

#define FF 20
#define NI 190         // F*(F-1)/2
#define NIP 192        // padded
#define BB 4096
#define FD 320         // F*D
#define PV 20          // padded row stride (floats) for s_v
#define KH 160         // K-half for k_w12 split
#define KQ 80          // K-quarter for k_w split

// K1 (split-K x2, measured good in r11): partial W12[h][320][192]
// over k in [h*160, h*160+160). Grid (320,2): 2.5 blocks/CU, K-chain 160.
__global__ __launch_bounds__(192) void k_w12(const float* __restrict__ w1,
                                             const float* __restrict__ w2,
                                             float* __restrict__ W12p) {
    __shared__ float srow[KH];
    int r = blockIdx.x;
    int h = blockIdx.y;            // K-half
    int k0 = h * KH;
    for (int j = threadIdx.x; j < KH; j += 192) srow[j] = w1[r * FD + k0 + j];
    __syncthreads();
    int c = threadIdx.x;   // 0..191
    float acc = 0.f;
    if (c < NI) {
        for (int k = 0; k < KH; ++k) acc += srow[k] * w2[(k0 + k) * NI + c];
    }
    W12p[h * (FD * NIP) + r * NIP + c] = acc;   // cols 190,191 get 0
}

// K2 (round-13: split-K x4, 16-deep tiles): partial w[q][4096][192] over
// W12-rows [q*80, q*80+80). Grid (64,3,4) = 768 blocks = 3/CU UNIFORM
// (was 384 = 1.5/CU imbalanced: 128 CUs carried 2 blocks, 128 carried 1),
// 12 waves/CU (2x TLP). Per-step FMA:ds_read ratio UNCHANGED at 8:1
// (256 FMA vs 32 b128/thread); staging 3 prefetched float4/thread/step.
// Same T14 prefetch skeleton, 5 steps. k_main sums the 4 partials.
__global__ __launch_bounds__(256) void k_w(const float* __restrict__ z,
                                           const float* __restrict__ W12p,
                                           float* __restrict__ wout) {
    __shared__ float zT[16][68];
    __shared__ float Ws[16][64];
    const float* __restrict__ W12b = W12p + FD * NIP;
    int b0 = blockIdx.x * 64;
    int c0 = blockIdx.y * 64;
    int kbase = blockIdx.z * KQ;   // K-quarter base
    int t = threadIdx.x;
    int tr = t >> 4, tc = t & 15;
    float acc[4][4];
#pragma unroll
    for (int i = 0; i < 4; ++i)
#pragma unroll
        for (int j = 0; j < 4; ++j) acc[i][j] = 0.f;

    // staging task maps (1 z-float4 + 1 W-float4-pair per thread per step)
    int zrow = t >> 2, zch = t & 3;    // z: 64 rows x 4 chunks (16 k)
    int kr = t >> 4,  cq = t & 15;     // W: 16 k-rows x 16 float4-cols

    // prologue: stage step 0 of this K-quarter
    float4 vz = *(const float4*)&z[(b0 + zrow) * FD + kbase + zch * 4];
    float4 va = *(const float4*)&W12p[(kbase + kr) * NIP + c0 + cq * 4];
    float4 vb = *(const float4*)&W12b[(kbase + kr) * NIP + c0 + cq * 4];
    zT[zch * 4 + 0][zrow] = vz.x;
    zT[zch * 4 + 1][zrow] = vz.y;
    zT[zch * 4 + 2][zrow] = vz.z;
    zT[zch * 4 + 3][zrow] = vz.w;
    *(float4*)&Ws[kr][cq * 4] =
        make_float4(va.x + vb.x, va.y + vb.y, va.z + vb.z, va.w + vb.w);
    __syncthreads();

    for (int ks = 0; ks < KQ; ks += 16) {
        bool more = (ks + 16) < KQ;
        if (more) {   // issue next-step loads; they fly under the FMA loop
            vz = *(const float4*)&z[(b0 + zrow) * FD + kbase + (ks + 16) + zch * 4];
            va = *(const float4*)&W12p[(kbase + ks + 16 + kr) * NIP + c0 + cq * 4];
            vb = *(const float4*)&W12b[(kbase + ks + 16 + kr) * NIP + c0 + cq * 4];
        }
#pragma unroll
        for (int k = 0; k < 16; ++k) {
            float4 zb = *(const float4*)&zT[k][tr * 4];
            float4 wv = *(const float4*)&Ws[k][tc * 4];
            float zz[4] = {zb.x, zb.y, zb.z, zb.w};
            float ww[4] = {wv.x, wv.y, wv.z, wv.w};
#pragma unroll
            for (int i = 0; i < 4; ++i)
#pragma unroll
                for (int j = 0; j < 4; ++j) acc[i][j] += zz[i] * ww[j];
        }
        if (more) {
            __syncthreads();   // all reads of current tile done
            zT[zch * 4 + 0][zrow] = vz.x;
            zT[zch * 4 + 1][zrow] = vz.y;
            zT[zch * 4 + 2][zrow] = vz.z;
            zT[zch * 4 + 3][zrow] = vz.w;
            *(float4*)&Ws[kr][cq * 4] =
                make_float4(va.x + vb.x, va.y + vb.y, va.z + vb.z, va.w + vb.w);
            __syncthreads();   // writes visible
        }
    }
#pragma unroll
    for (int i = 0; i < 4; ++i) {
        float4 v = make_float4(acc[i][0], acc[i][1], acc[i][2], acc[i][3]);
        *(float4*)&wout[(size_t)blockIdx.z * (BB * NIP) +
                        (b0 + tr * 4 + i) * NIP + c0 + tc * 4] = v;
    }
}

// K3: pair-major stage-once (round-2 core, in every best config).
// One change vs r12: s_w sums FOUR k_w split-K partials.
#define SA(f, h, d) ((f) * 33 + (h) * 16 + (d))
__global__ __launch_bounds__(320) void k_main(const float* __restrict__ cb,   // [500000][16]
                                              const float* __restrict__ Wt,   // [32][16]
                                              const int* __restrict__ hidx,   // [2][B][NI]
                                              const int* __restrict__ iidx,   // [20][19]
                                              const float* __restrict__ wbuf, // [4][B][192]
                                              float* __restrict__ out) {      // [B][20][16]
    __shared__ int s_i0[NI], s_i1[NI];
    __shared__ float s_w[NI];
    __shared__ int s_plist[FF * 19];
    __shared__ float s_W[32 * 16];
    __shared__ __align__(16) float s_v[NI * PV];
    __shared__ float s_acc[19 * 33 + 2 * 16 + 16];

    int t = threadIdx.x;
    int b = blockIdx.x;

    if (t < NI) {
        s_i0[t] = hidx[b * NI + t];
        s_i1[t] = hidx[(BB + b) * NI + t];
        s_w[t] = wbuf[b * NIP + t] + wbuf[(size_t)BB * NIP + b * NIP + t]
               + wbuf[2 * (size_t)BB * NIP + b * NIP + t]
               + wbuf[3 * (size_t)BB * NIP + b * NIP + t];
    }
    for (int j = t; j < FF * 19; j += 320) s_plist[j] = iidx[j];
    for (int j = t; j < 512; j += 320) s_W[j] = Wt[j];
    __syncthreads();

    const float4* cb4 = (const float4*)cb;
    int q  = t & 3;    // quad within a 16-float row
    int pb = t >> 2;   // 0..79  (pair base; pairs pb, pb+80, pb+160)
    bool has3 = pb < (NI - 160);   // pb < 30

    // ---- Phase A0: gather hash0 rows (x w) ----
    float4 g0a = cb4[s_i0[pb] * 4 + q];
    float4 g0b = cb4[s_i0[pb + 80] * 4 + q];
    float4 g0c;
    if (has3) g0c = cb4[s_i0[pb + 160] * 4 + q];
    float w_a = s_w[pb], w_b = s_w[pb + 80];
    float w_c = has3 ? s_w[pb + 160] : 0.f;

    *(float4*)&s_v[pb * PV + q * 4] =
        make_float4(g0a.x * w_a, g0a.y * w_a, g0a.z * w_a, g0a.w * w_a);
    *(float4*)&s_v[(pb + 80) * PV + q * 4] =
        make_float4(g0b.x * w_b, g0b.y * w_b, g0b.z * w_b, g0b.w * w_b);
    if (has3)
        *(float4*)&s_v[(pb + 160) * PV + q * 4] =
            make_float4(g0c.x * w_c, g0c.y * w_c, g0c.z * w_c, g0c.w * w_c);
    __syncthreads();

    // ---- Issue hash1 gathers now; they fly under Phase B0's LDS work ----
    float4 g1a = cb4[s_i1[pb] * 4 + q];
    float4 g1b = cb4[s_i1[pb + 80] * 4 + q];
    float4 g1c;
    if (has3) g1c = cb4[s_i1[pb + 160] * 4 + q];

    // ---- Phase B0: per-field accumulate from LDS ----
    int f = t >> 4, d = t & 15;
    const int* pl = &s_plist[f * 19];
    float a0 = 0.f;
#pragma unroll
    for (int j = 0; j < 19; ++j) a0 += s_v[pl[j] * PV + d];
    __syncthreads();   // B0 reads done before s_v overwrite

    *(float4*)&s_v[pb * PV + q * 4] =
        make_float4(g1a.x * w_a, g1a.y * w_a, g1a.z * w_a, g1a.w * w_a);
    *(float4*)&s_v[(pb + 80) * PV + q * 4] =
        make_float4(g1b.x * w_b, g1b.y * w_b, g1b.z * w_b, g1b.w * w_b);
    if (has3)
        *(float4*)&s_v[(pb + 160) * PV + q * 4] =
            make_float4(g1c.x * w_c, g1c.y * w_c, g1c.z * w_c, g1c.w * w_c);
    __syncthreads();

    // ---- Phase B1 ----
    float a1 = 0.f;
#pragma unroll
    for (int j = 0; j < 19; ++j) a1 += s_v[pl[j] * PV + d];

    s_acc[SA(f, 0, d)] = a0;
    s_acc[SA(f, 1, d)] = a1;
    __syncthreads();

    // ---- Transform: out[b,f,d] = sum_k acc0[f][k]*W[k][d] + acc1[f][k]*W[16+k][d]
    float r = 0.f;
#pragma unroll
    for (int k = 0; k < 16; ++k) {
        r += s_acc[SA(f, 0, k)] * s_W[k * 16 + d];
        r += s_acc[SA(f, 1, k)] * s_W[(16 + k) * 16 + d];
    }
    out[b * FD + t] = r;
}

extern "C" void kernel_launch(void* const* d_in, const int* in_sizes, int n_in,
                              void* d_out, int out_size, void* d_ws, size_t ws_size,
                              hipStream_t stream) {
    const float* origin = (const float*)d_in[0];  // (B, F, D) = z
    const float* cb     = (const float*)d_in[1];  // (500000, 16)
    const float* Wt     = (const float*)d_in[2];  // (32, 16)
    const float* w1     = (const float*)d_in[3];  // (320, 320)
    const float* w2     = (const float*)d_in[4];  // (320, 190)
    const int*   hidx   = (const int*)d_in[5];    // (2, B, 190)
    const int*   iidx   = (const int*)d_in[6];    // (20, 19)
    float* out = (float*)d_out;

    float* W12p = (float*)d_ws;               // 2 x 320*192 floats (split-K partials)
    float* wbuf = W12p + 2 * FD * NIP;        // 4 x 4096*192 floats (split-K partials)

    k_w12<<<dim3(FD, 2), 192, 0, stream>>>(w1, w2, W12p);
    dim3 gw(BB / 64, 3, 4);
    k_w<<<gw, 256, 0, stream>>>(origin, W12p, wbuf);
    k_main<<<BB, 320, 0, stream>>>(cb, Wt, hidx, iidx, wbuf, out);
}

// Round 16
// 130.839 us; speedup vs baseline: 1.1464x; 1.0296x over previous
//
#include <hip/hip_runtime.h>

#define FF 20
#define NI 190         // F*(F-1)/2
#define NIP 192        // padded
#define BB 4096
#define FD 320         // F*D
#define PV 20          // padded row stride (floats) for s_v
#define KQ 80          // K-quarter (k_w12 and k_w splits)

// K1 (split-K x4): partial W12[h][320][192] over k in [h*80, h*80+80).
// Grid (320,4) = 1280 blocks = 5/CU (15 waves/CU), K-chain 80 (was 160 @2.5/CU).
// k_w sums the four partials during staging.
__global__ __launch_bounds__(192) void k_w12(const float* __restrict__ w1,
                                             const float* __restrict__ w2,
                                             float* __restrict__ W12p) {
    __shared__ float srow[KQ];
    int r = blockIdx.x;
    int h = blockIdx.y;            // K-quarter
    int k0 = h * KQ;
    for (int j = threadIdx.x; j < KQ; j += 192) srow[j] = w1[r * FD + k0 + j];
    __syncthreads();
    int c = threadIdx.x;   // 0..191
    float acc = 0.f;
    if (c < NI) {
        for (int k = 0; k < KQ; ++k) acc += srow[k] * w2[(k0 + k) * NI + c];
    }
    W12p[h * (FD * NIP) + r * NIP + c] = acc;   // cols 190,191 get 0
}

// K2 (r13 structure, measured -0.95us): split-K x4 over FD, 16-deep tiles,
// grid (64,3,4) = 768 blocks = 3/CU uniform, T14 register prefetch.
// r14 change: staging sums FOUR W12 partials (5 prefetched float4/thread/step,
// hidden under the 256-FMA loop; FMA:ds_read ratio unchanged).
__global__ __launch_bounds__(256) void k_w(const float* __restrict__ z,
                                           const float* __restrict__ W12p,
                                           float* __restrict__ wout) {
    __shared__ float zT[16][68];
    __shared__ float Ws[16][64];
    const float* __restrict__ W1 = W12p + FD * NIP;
    const float* __restrict__ W2 = W12p + 2 * (FD * NIP);
    const float* __restrict__ W3 = W12p + 3 * (FD * NIP);
    int b0 = blockIdx.x * 64;
    int c0 = blockIdx.y * 64;
    int kbase = blockIdx.z * KQ;   // K-quarter base (over FD)
    int t = threadIdx.x;
    int tr = t >> 4, tc = t & 15;
    float acc[4][4];
#pragma unroll
    for (int i = 0; i < 4; ++i)
#pragma unroll
        for (int j = 0; j < 4; ++j) acc[i][j] = 0.f;

    // staging task maps
    int zrow = t >> 2, zch = t & 3;    // z: 64 rows x 4 chunks (16 k)
    int kr = t >> 4,  cq = t & 15;     // W: 16 k-rows x 16 float4-cols

    // prologue: stage step 0 of this K-quarter
    float4 vz = *(const float4*)&z[(b0 + zrow) * FD + kbase + zch * 4];
    float4 va = *(const float4*)&W12p[(kbase + kr) * NIP + c0 + cq * 4];
    float4 vb = *(const float4*)&W1[(kbase + kr) * NIP + c0 + cq * 4];
    float4 vc = *(const float4*)&W2[(kbase + kr) * NIP + c0 + cq * 4];
    float4 vd = *(const float4*)&W3[(kbase + kr) * NIP + c0 + cq * 4];
    zT[zch * 4 + 0][zrow] = vz.x;
    zT[zch * 4 + 1][zrow] = vz.y;
    zT[zch * 4 + 2][zrow] = vz.z;
    zT[zch * 4 + 3][zrow] = vz.w;
    *(float4*)&Ws[kr][cq * 4] =
        make_float4(va.x + vb.x + vc.x + vd.x, va.y + vb.y + vc.y + vd.y,
                    va.z + vb.z + vc.z + vd.z, va.w + vb.w + vc.w + vd.w);
    __syncthreads();

    for (int ks = 0; ks < KQ; ks += 16) {
        bool more = (ks + 16) < KQ;
        if (more) {   // issue next-step loads; they fly under the FMA loop
            vz = *(const float4*)&z[(b0 + zrow) * FD + kbase + (ks + 16) + zch * 4];
            va = *(const float4*)&W12p[(kbase + ks + 16 + kr) * NIP + c0 + cq * 4];
            vb = *(const float4*)&W1[(kbase + ks + 16 + kr) * NIP + c0 + cq * 4];
            vc = *(const float4*)&W2[(kbase + ks + 16 + kr) * NIP + c0 + cq * 4];
            vd = *(const float4*)&W3[(kbase + ks + 16 + kr) * NIP + c0 + cq * 4];
        }
#pragma unroll
        for (int k = 0; k < 16; ++k) {
            float4 zb = *(const float4*)&zT[k][tr * 4];
            float4 wv = *(const float4*)&Ws[k][tc * 4];
            float zz[4] = {zb.x, zb.y, zb.z, zb.w};
            float ww[4] = {wv.x, wv.y, wv.z, wv.w};
#pragma unroll
            for (int i = 0; i < 4; ++i)
#pragma unroll
                for (int j = 0; j < 4; ++j) acc[i][j] += zz[i] * ww[j];
        }
        if (more) {
            __syncthreads();   // all reads of current tile done
            zT[zch * 4 + 0][zrow] = vz.x;
            zT[zch * 4 + 1][zrow] = vz.y;
            zT[zch * 4 + 2][zrow] = vz.z;
            zT[zch * 4 + 3][zrow] = vz.w;
            *(float4*)&Ws[kr][cq * 4] =
                make_float4(va.x + vb.x + vc.x + vd.x, va.y + vb.y + vc.y + vd.y,
                            va.z + vb.z + vc.z + vd.z, va.w + vb.w + vc.w + vd.w);
            __syncthreads();   // writes visible
        }
    }
#pragma unroll
    for (int i = 0; i < 4; ++i) {
        float4 v = make_float4(acc[i][0], acc[i][1], acc[i][2], acc[i][3]);
        *(float4*)&wout[(size_t)blockIdx.z * (BB * NIP) +
                        (b0 + tr * 4 + i) * NIP + c0 + tc * 4] = v;
    }
}

// K3: pair-major stage-once (round-2 core, in every best config).
// s_w sums the four k_w split-K partials (unchanged from r13).
#define SA(f, h, d) ((f) * 33 + (h) * 16 + (d))
__global__ __launch_bounds__(320) void k_main(const float* __restrict__ cb,   // [500000][16]
                                              const float* __restrict__ Wt,   // [32][16]
                                              const int* __restrict__ hidx,   // [2][B][NI]
                                              const int* __restrict__ iidx,   // [20][19]
                                              const float* __restrict__ wbuf, // [4][B][192]
                                              float* __restrict__ out) {      // [B][20][16]
    __shared__ int s_i0[NI], s_i1[NI];
    __shared__ float s_w[NI];
    __shared__ int s_plist[FF * 19];
    __shared__ float s_W[32 * 16];
    __shared__ __align__(16) float s_v[NI * PV];
    __shared__ float s_acc[19 * 33 + 2 * 16 + 16];

    int t = threadIdx.x;
    int b = blockIdx.x;

    if (t < NI) {
        s_i0[t] = hidx[b * NI + t];
        s_i1[t] = hidx[(BB + b) * NI + t];
        s_w[t] = wbuf[b * NIP + t] + wbuf[(size_t)BB * NIP + b * NIP + t]
               + wbuf[2 * (size_t)BB * NIP + b * NIP + t]
               + wbuf[3 * (size_t)BB * NIP + b * NIP + t];
    }
    for (int j = t; j < FF * 19; j += 320) s_plist[j] = iidx[j];
    for (int j = t; j < 512; j += 320) s_W[j] = Wt[j];
    __syncthreads();

    const float4* cb4 = (const float4*)cb;
    int q  = t & 3;    // quad within a 16-float row
    int pb = t >> 2;   // 0..79  (pair base; pairs pb, pb+80, pb+160)
    bool has3 = pb < (NI - 160);   // pb < 30

    // ---- Phase A0: gather hash0 rows (x w) ----
    float4 g0a = cb4[s_i0[pb] * 4 + q];
    float4 g0b = cb4[s_i0[pb + 80] * 4 + q];
    float4 g0c;
    if (has3) g0c = cb4[s_i0[pb + 160] * 4 + q];
    float w_a = s_w[pb], w_b = s_w[pb + 80];
    float w_c = has3 ? s_w[pb + 160] : 0.f;

    *(float4*)&s_v[pb * PV + q * 4] =
        make_float4(g0a.x * w_a, g0a.y * w_a, g0a.z * w_a, g0a.w * w_a);
    *(float4*)&s_v[(pb + 80) * PV + q * 4] =
        make_float4(g0b.x * w_b, g0b.y * w_b, g0b.z * w_b, g0b.w * w_b);
    if (has3)
        *(float4*)&s_v[(pb + 160) * PV + q * 4] =
            make_float4(g0c.x * w_c, g0c.y * w_c, g0c.z * w_c, g0c.w * w_c);
    __syncthreads();

    // ---- Issue hash1 gathers now; they fly under Phase B0's LDS work ----
    float4 g1a = cb4[s_i1[pb] * 4 + q];
    float4 g1b = cb4[s_i1[pb + 80] * 4 + q];
    float4 g1c;
    if (has3) g1c = cb4[s_i1[pb + 160] * 4 + q];

    // ---- Phase B0: per-field accumulate from LDS ----
    int f = t >> 4, d = t & 15;
    const int* pl = &s_plist[f * 19];
    float a0 = 0.f;
#pragma unroll
    for (int j = 0; j < 19; ++j) a0 += s_v[pl[j] * PV + d];
    __syncthreads();   // B0 reads done before s_v overwrite

    *(float4*)&s_v[pb * PV + q * 4] =
        make_float4(g1a.x * w_a, g1a.y * w_a, g1a.z * w_a, g1a.w * w_a);
    *(float4*)&s_v[(pb + 80) * PV + q * 4] =
        make_float4(g1b.x * w_b, g1b.y * w_b, g1b.z * w_b, g1b.w * w_b);
    if (has3)
        *(float4*)&s_v[(pb + 160) * PV + q * 4] =
            make_float4(g1c.x * w_c, g1c.y * w_c, g1c.z * w_c, g1c.w * w_c);
    __syncthreads();

    // ---- Phase B1 ----
    float a1 = 0.f;
#pragma unroll
    for (int j = 0; j < 19; ++j) a1 += s_v[pl[j] * PV + d];

    s_acc[SA(f, 0, d)] = a0;
    s_acc[SA(f, 1, d)] = a1;
    __syncthreads();

    // ---- Transform: out[b,f,d] = sum_k acc0[f][k]*W[k][d] + acc1[f][k]*W[16+k][d]
    float r = 0.f;
#pragma unroll
    for (int k = 0; k < 16; ++k) {
        r += s_acc[SA(f, 0, k)] * s_W[k * 16 + d];
        r += s_acc[SA(f, 1, k)] * s_W[(16 + k) * 16 + d];
    }
    out[b * FD + t] = r;
}

extern "C" void kernel_launch(void* const* d_in, const int* in_sizes, int n_in,
                              void* d_out, int out_size, void* d_ws, size_t ws_size,
                              hipStream_t stream) {
    const float* origin = (const float*)d_in[0];  // (B, F, D) = z
    const float* cb     = (const float*)d_in[1];  // (500000, 16)
    const float* Wt     = (const float*)d_in[2];  // (32, 16)
    const float* w1     = (const float*)d_in[3];  // (320, 320)
    const float* w2     = (const float*)d_in[4];  // (320, 190)
    const int*   hidx   = (const int*)d_in[5];    // (2, B, 190)
    const int*   iidx   = (const int*)d_in[6];    // (20, 19)
    float* out = (float*)d_out;

    float* W12p = (float*)d_ws;               // 4 x 320*192 floats (split-K partials)
    float* wbuf = W12p + 4 * (FD * NIP);      // 4 x 4096*192 floats (split-K partials)

    k_w12<<<dim3(FD, 4), 192, 0, stream>>>(w1, w2, W12p);
    dim3 gw(BB / 64, 3, 4);
    k_w<<<gw, 256, 0, stream>>>(origin, W12p, wbuf);
    k_main<<<BB, 320, 0, stream>>>(cb, Wt, hidx, iidx, wbuf, out);
}